// Round 1
// baseline (92.796 us; speedup 1.0000x reference)
//
#include <hip/hip_runtime.h>

// PureAEVComputer radial AEV on MI355X — R3: species bucket-sort + uniform chunks.
// B=16, N=512, S=4 species, R=16 shifts, pad to 1008.
//
// Graph timing note: the 81.4us bench includes a 43us 256MiB workspace poison
// and ~5.5us output poison (harness-side, at HBM peak). Kernel itself ~33us.
// This round: (a) bucket-sort neighbors by species in LDS so j-chunks are
// wave-uniform -> 1 pk_fma per h instead of 4 masked ones; (b) t-recurrence
// for the exponent kills the 32 hoisted packed-constant VGPRs (occupancy).
//
// One wave per atom i (8 waves/block); lanes = neighbor j within 64-chunk.
// core_r = exp(-16(d-s_r)^2) = exp2(-L16*t^2), t = d - s_r, t -= 0.5375/step.
// Per-lane acc = f2[32] (s-major), packed v_pk_fma accumulate.
// Epilogue: 5-level f2 reduce-scatter + 1 float exchange -> lane l owns feat l.

typedef float f2 __attribute__((ext_vector_type(2)));

constexpr int B = 16;
constexpr int N = 512;
constexpr int TARGET = 1008;
constexpr float L16 = 23.083120654223414f;  // 16 * log2(e)

__global__ __launch_bounds__(512) void aev_radial_kernel(
    const int* __restrict__ species,       // (B, N)
    const float* __restrict__ coordinates, // (B, N, 3)
    float* __restrict__ out)               // (B, N, 1008)
{
    __shared__ float4 sc[N];   // bucket-sorted by species: xyz + species in .w
    __shared__ int hist[4];
    __shared__ int cursor[4];
    __shared__ int tags[8];    // per-64-chunk: uniform species id, or -1

    const int tid  = threadIdx.x;
    const int lane = tid & 63;
    const int wave = tid >> 6;
    const int bb   = blockIdx.x >> 6;    // 64 blocks per batch
    const int tile = blockIdx.x & 63;    // 8-atom tile

    const float* cb = coordinates + (size_t)bb * (N * 3);
    const int*   sb = species + bb * N;

    // ---- one atom per thread; two-pass ballot bucket-sort into sc ----
    const int   sp = sb[tid];
    const float ax = cb[3 * tid], ay = cb[3 * tid + 1], az = cb[3 * tid + 2];

    if (tid < 4) hist[tid] = 0;
    __syncthreads();

    {
        const uint64_t m0 = __ballot(sp == 0);
        const uint64_t m1 = __ballot(sp == 1);
        const uint64_t m2 = __ballot(sp == 2);
        const uint64_t m3 = __ballot(sp == 3);
        if      (lane == 0) atomicAdd(&hist[0], (int)__popcll(m0));
        else if (lane == 1) atomicAdd(&hist[1], (int)__popcll(m1));
        else if (lane == 2) atomicAdd(&hist[2], (int)__popcll(m2));
        else if (lane == 3) atomicAdd(&hist[3], (int)__popcll(m3));
    }
    __syncthreads();

    if (tid == 0) {
        cursor[0] = 0;
        cursor[1] = hist[0];
        cursor[2] = hist[0] + hist[1];
        cursor[3] = hist[0] + hist[1] + hist[2];
    }
    __syncthreads();

    {
        const uint64_t below = (1ull << lane) - 1ull;
        #pragma unroll
        for (int s = 0; s < 4; ++s) {
            const uint64_t ms = __ballot(sp == s);
            if (ms) {  // wave-uniform branch
                const int leader = __ffsll((unsigned long long)ms) - 1;
                int start = 0;
                if (lane == leader) start = atomicAdd(&cursor[s], (int)__popcll(ms));
                start = __shfl(start, leader, 64);
                if (sp == s) {
                    const int rank = (int)__popcll(ms & below);
                    sc[start + rank] = make_float4(ax, ay, az, __int_as_float(s));
                }
            }
        }
    }
    __syncthreads();

    if (tid < 8) {  // sorted => chunk uniform iff endpoints match
        const int sA = __float_as_int(sc[tid * 64 +  0].w);
        const int sB = __float_as_int(sc[tid * 64 + 63].w);
        tags[tid] = (sA == sB) ? sA : -1;
    }
    __syncthreads();

    // ---- main loop: one wave per atom i ----
    const int i = tile * 8 + wave;
    const float cix = cb[3 * i], ciy = cb[3 * i + 1], ciz = cb[3 * i + 2];

    f2 acc[32];
    #pragma unroll
    for (int k = 0; k < 32; ++k) acc[k] = f2{0.0f, 0.0f};

    const f2 nl16  = {-L16, -L16};
    const f2 stepv = {-0.5375f, -0.5375f};   // -2*delta, both shift slots

#define UNI_CHUNK(S)                                              \
    {                                                             \
        f2 t = t0;                                                \
        _Pragma("unroll")                                         \
        for (int h = 0; h < 8; ++h) {                             \
            const f2 e = (t * nl16) * t;                          \
            f2 core;                                              \
            core.x = __builtin_amdgcn_exp2f(e.x);                 \
            core.y = __builtin_amdgcn_exp2f(e.y);                 \
            acc[S * 8 + h] += core * fcv;                         \
            t += stepv;                                           \
        }                                                         \
    }

    #pragma unroll 1
    for (int c = 0; c < 8; ++c) {
        const float4 cj = sc[c * 64 + lane];        // ds_read_b128
        const float dx = cix - cj.x;
        const float dy = ciy - cj.y;
        const float dz = ciz - cj.z;
        const float sq = dx * dx + dy * dy + dz * dz;
        const float d  = __builtin_amdgcn_sqrtf(sq);

        const bool valid = (d > 0.0f) && (d <= 5.2f);
        float fc = 0.5f * __builtin_amdgcn_cosf(d * (1.0f / 10.4f)) + 0.5f;
        fc = valid ? fc : 0.0f;

        const f2 fcv = {fc, fc};
        const f2 t0  = {d - 0.9f, d - 1.16875f};    // t_r = d - s_r, slots r=2h,2h+1
        const int tag = __builtin_amdgcn_readfirstlane(tags[c]);

        if      (tag == 0) UNI_CHUNK(0)
        else if (tag == 1) UNI_CHUNK(1)
        else if (tag == 2) UNI_CHUNK(2)
        else if (tag == 3) UNI_CHUNK(3)
        else {  // mixed boundary chunk (<=3 of 8): original masked path
            const int spj = __float_as_int(cj.w);
            const f2 z2 = {0.0f, 0.0f};
            const f2 f0 = (spj == 0) ? fcv : z2;
            const f2 f1 = (spj == 1) ? fcv : z2;
            const f2 f2m = (spj == 2) ? fcv : z2;
            const f2 f3 = (spj == 3) ? fcv : z2;
            f2 t = t0;
            #pragma unroll
            for (int h = 0; h < 8; ++h) {
                const f2 e = (t * nl16) * t;
                f2 core;
                core.x = __builtin_amdgcn_exp2f(e.x);
                core.y = __builtin_amdgcn_exp2f(e.y);
                acc[0 * 8 + h] += core * f0;
                acc[1 * 8 + h] += core * f1;
                acc[2 * 8 + h] += core * f2m;
                acc[3 * 8 + h] += core * f3;
                t += stepv;
            }
        }
    }
#undef UNI_CHUNK

    // ---- Reduce-scatter: 5 f2 levels (m=32..2), then one float exchange ----
    int cnt = 32;
    #pragma unroll
    for (int m = 32; m >= 2; m >>= 1) {
        const int half = cnt >> 1;
        const bool up = (lane & m) != 0;
        #pragma unroll
        for (int k = 0; k < half; ++k) {
            const f2 keep = up ? acc[k + half] : acc[k];
            const f2 send = up ? acc[k] : acc[k + half];
            f2 r;
            r.x = __shfl_xor(send.x, m, 64);
            r.y = __shfl_xor(send.y, m, 64);
            acc[k] = keep + r;
        }
        cnt = half;
    }
    const bool hi = (lane & 1) != 0;
    const float send = hi ? acc[0].x : acc[0].y;
    const float recv = __shfl_xor(send, 1, 64);
    const float mine = (hi ? acc[0].y : acc[0].x) + recv;

    float* row = out + (size_t)(bb * N + i) * TARGET;
    row[lane] = mine;
    float4* row4 = reinterpret_cast<float4*>(row);
    const float4 z4 = make_float4(0.0f, 0.0f, 0.0f, 0.0f);
    #pragma unroll
    for (int idx = 16 + lane; idx < 252; idx += 64) row4[idx] = z4;
}

extern "C" void kernel_launch(void* const* d_in, const int* in_sizes, int n_in,
                              void* d_out, int out_size, void* d_ws, size_t ws_size,
                              hipStream_t stream) {
    const int*   species     = (const int*)d_in[0];
    const float* coordinates = (const float*)d_in[1];
    float*       out         = (float*)d_out;

    dim3 grid(B * 64), block(512);  // 8 waves = 8 atoms per block
    hipLaunchKernelGGL(aev_radial_kernel, grid, block, 0, stream,
                       species, coordinates, out);
}

// Round 2
// 80.661 us; speedup vs baseline: 1.1504x; 1.1504x over previous
//
#include <hip/hip_runtime.h>

// PureAEVComputer radial AEV on MI355X — R4: R2 structure + VGPR-pressure cut.
// B=16, N=512, S=4 species, R=16 shifts, pad to 1008.
//
// Theory: R2 (81.4us dur, kernel ~33us) was latency-bound at ~15% issue
// utilization because acc[32] (64 VGPR) + 16 hoisted packed shift-constant
// pairs (32 VGPR, VOP3P can't take literals) pushed VGPRs >128 -> 2 waves/SIMD.
// Fix: t-recurrence (2 const pairs instead of 32 VGPRs of constants),
// __launch_bounds__(256,4) to force <=128 VGPR / 4 waves per SIMD,
// and explicit next-chunk LDS prefetch. R3's sort/branch structure reverted
// (regressed to 92.8us).
//
// One wave per atom i; lanes = neighbor j within 64-chunk.
// core_r = exp(-16(d-s_r)^2) = exp2(-L16*t^2), t = d - s_r, t -= 0.5375 per h.
// Per-lane acc = f2[32] (s-major), packed v_pk ops.
// Epilogue: 5-level f2 reduce-scatter + 1 float exchange -> lane l owns feat l.

typedef float f2 __attribute__((ext_vector_type(2)));

constexpr int B = 16;
constexpr int N = 512;
constexpr int TARGET = 1008;
constexpr float L16 = 23.083120654223414f;  // 16 * log2(e)

__global__ __launch_bounds__(256, 4) void aev_radial_kernel(
    const int* __restrict__ species,       // (B, N)
    const float* __restrict__ coordinates, // (B, N, 3)
    float* __restrict__ out)               // (B, N, 1008)
{
    __shared__ float4 sc[N];  // xyz + species bits in .w

    const int tid  = threadIdx.x;
    const int bb   = blockIdx.x >> 7;    // batch (128 blocks per batch)
    const int tile = blockIdx.x & 127;   // 4-atom tile

    const float* cb = coordinates + (size_t)bb * (N * 3);
    const int*   sb = species + bb * N;
    for (int a = tid; a < N; a += 256) {
        sc[a] = make_float4(cb[3 * a], cb[3 * a + 1], cb[3 * a + 2],
                            __int_as_float(sb[a]));
    }
    __syncthreads();

    const int wave = tid >> 6;
    const int lane = tid & 63;
    const int i    = tile * 4 + wave;

    const float4 ci = sc[i];

    f2 acc[32];
    #pragma unroll
    for (int k = 0; k < 32; ++k) acc[k] = f2{0.0f, 0.0f};

    const f2 nl16  = {-L16, -L16};
    const f2 stepv = {-0.5375f, -0.5375f};   // -2*shift_delta, both slots
    const f2 z2    = {0.0f, 0.0f};

    float4 cj = sc[lane];
    #pragma unroll 1
    for (int jc = 0; jc < N; jc += 64) {
        // prefetch next chunk (wraps harmlessly on last iter)
        const float4 cjn = sc[((jc + 64) & (N - 1)) + lane];

        const float dx = ci.x - cj.x;
        const float dy = ci.y - cj.y;
        const float dz = ci.z - cj.z;
        const float sq = dx * dx + dy * dy + dz * dz;
        const float d  = __builtin_amdgcn_sqrtf(sq);
        const int spj  = __float_as_int(cj.w);

        const bool valid = (d > 0.0f) && (d <= 5.2f);
        // fc = 0.5*cos(pi*d/5.2)+0.5 ; v_cos takes revolutions: d/10.4
        float fc = 0.5f * __builtin_amdgcn_cosf(d * (1.0f / 10.4f)) + 0.5f;
        fc = valid ? fc : 0.0f;

        const f2 fcv = {fc, fc};
        const f2 f0 = (spj == 0) ? fcv : z2;
        const f2 f1 = (spj == 1) ? fcv : z2;
        const f2 fm2 = (spj == 2) ? fcv : z2;
        const f2 f3 = (spj == 3) ? fcv : z2;

        f2 t = {d - 0.9f, d - 1.16875f};   // t_r = d - s_r for slots r=2h,2h+1
        #pragma unroll
        for (int h = 0; h < 8; ++h) {
            const f2 u = t * nl16;          // v_pk_mul_f32
            const f2 e = u * t;             // v_pk_mul_f32  (= -L16*t^2)
            f2 core;
            core.x = __builtin_amdgcn_exp2f(e.x);
            core.y = __builtin_amdgcn_exp2f(e.y);
            acc[0 * 8 + h] += core * f0;    // v_pk_fma_f32 x4
            acc[1 * 8 + h] += core * f1;
            acc[2 * 8 + h] += core * fm2;
            acc[3 * 8 + h] += core * f3;
            t += stepv;                     // v_pk_add_f32
        }
        cj = cjn;
    }

    // Reduce-scatter: 5 f2 levels (m=32..2), then one float exchange (m=1).
    int cnt = 32;
    #pragma unroll
    for (int m = 32; m >= 2; m >>= 1) {
        const int half = cnt >> 1;
        const bool up = (lane & m) != 0;
        #pragma unroll
        for (int k = 0; k < half; ++k) {
            const f2 keep = up ? acc[k + half] : acc[k];
            const f2 send = up ? acc[k] : acc[k + half];
            f2 r;
            r.x = __shfl_xor(send.x, m, 64);
            r.y = __shfl_xor(send.y, m, 64);
            acc[k] = keep + r;
        }
        cnt = half;
    }
    // acc[0] = features {2t, 2t+1}, t = lane>>1, split by lane parity subsets.
    const bool hi = (lane & 1) != 0;
    const float send = hi ? acc[0].x : acc[0].y;
    const float recv = __shfl_xor(send, 1, 64);
    const float mine = (hi ? acc[0].y : acc[0].x) + recv;

    float* row = out + (size_t)(bb * N + i) * TARGET;
    row[lane] = mine;
    float4* row4 = reinterpret_cast<float4*>(row);
    const float4 z4 = make_float4(0.0f, 0.0f, 0.0f, 0.0f);
    #pragma unroll
    for (int idx = 16 + lane; idx < 252; idx += 64) row4[idx] = z4;
}

extern "C" void kernel_launch(void* const* d_in, const int* in_sizes, int n_in,
                              void* d_out, int out_size, void* d_ws, size_t ws_size,
                              hipStream_t stream) {
    const int*   species     = (const int*)d_in[0];
    const float* coordinates = (const float*)d_in[1];
    float*       out         = (float*)d_out;

    dim3 grid(B * 128), block(256);  // 4 waves = 4 atoms per block
    hipLaunchKernelGGL(aev_radial_kernel, grid, block, 0, stream,
                       species, coordinates, out);
}

// Round 3
// 78.315 us; speedup vs baseline: 1.1849x; 1.0300x over previous
//
#include <hip/hip_runtime.h>

// PureAEVComputer radial AEV on MI355X — R5: Gaussian-ladder recurrence.
// B=16, N=512, S=4 species, R=16 shifts, pad to 1008.
//
// Issue-bound theory (R2≈R4 at ~80.7us dur, kernel ~27us after ~48us harness
// fills): v_pk_*_f32 is 4cy/wave64 (fp32 packed is NOT double-rate on gfx950,
// peak 157.3TF = scalar rate), exp2/sqrt/cos ~8cy. R4 chunk ~400cy, dominated
// by 16 exp2/pair. This round: equispaced shifts => core_{k+2} = core_k * M_k,
// M_{k+2} = M_k * G2 (G2 = exp2(-8*L16*d^2) const). 16 exp2 -> 4 per pair
// (2 per 8-shift octave: start core + start multiplier).
// Numerics: E spans ~430 binary orders; fix = per-octave ladder + exponent
// offset F=96 inside the start exp2 (S_k = exp2(E_k+96) <= 2^96; flushes to 0
// only where true core < 2^-222), un-scaled by folding 2^-96 into fc once per
// chunk; d clamped to 5.2 for the ladder so multipliers stay finite (no 0*INF).
//
// One wave per atom i; lanes = neighbor j within 64-chunk.
// Per-lane acc = f2[32] (s-major, packed r-pairs). Epilogue: 5-level f2
// reduce-scatter + 1 float exchange -> lane l owns feature l.

typedef float f2 __attribute__((ext_vector_type(2)));

constexpr int B = 16;
constexpr int N = 512;
constexpr int TARGET = 1008;
constexpr float L16   = 23.083120654223414f;  // 16 * log2(e)
constexpr float TWOLD = 12.407177352895089f;  // 2*L16*delta   (delta = 0.26875)
constexpr float LD2   = 1.6672144570279266f;  // L16*delta^2
constexpr float FOFF  = 96.0f;                // exponent offset
constexpr float SCALE_DN = 1.2621774483536189e-29f;  // 2^-96

__global__ __launch_bounds__(256, 4) void aev_radial_kernel(
    const int* __restrict__ species,       // (B, N)
    const float* __restrict__ coordinates, // (B, N, 3)
    float* __restrict__ out)               // (B, N, 1008)
{
    __shared__ float4 sc[N];  // xyz + species bits in .w

    const int tid  = threadIdx.x;
    const int bb   = blockIdx.x >> 7;    // batch (128 blocks per batch)
    const int tile = blockIdx.x & 127;   // 4-atom tile

    const float* cb = coordinates + (size_t)bb * (N * 3);
    const int*   sb = species + bb * N;
    for (int a = tid; a < N; a += 256) {
        sc[a] = make_float4(cb[3 * a], cb[3 * a + 1], cb[3 * a + 2],
                            __int_as_float(sb[a]));
    }
    __syncthreads();

    const int wave = tid >> 6;
    const int lane = tid & 63;
    const int i    = tile * 4 + wave;

    const float4 ci = sc[i];

    // Ladder constants (one-time, 1 trans):
    // G1 = exp2(-2*L16*d^2), GH = G1^2, G2 = GH^2 = exp2(-8*L16*d^2)
    const float G1 = __builtin_amdgcn_exp2f(-2.0f * LD2);
    const float GH = G1 * G1;
    const float G2 = GH * GH;
    const f2 G2v = {G2, G2};

    f2 acc[32];
    #pragma unroll
    for (int k = 0; k < 32; ++k) acc[k] = f2{0.0f, 0.0f};

    const f2 z2 = {0.0f, 0.0f};

    // Octave ladder setup: shifts s_k = SFIRST + k*delta, k = 0..7.
    // corev = {S_0, S_1} with S_k = exp2(-L16*t_k^2 + 96), t_k = dc - s_k.
    // Mv = {M2_0, M2_1}: stride-2 multipliers, M2_{k+1} = M2_k*GH,
    // recurrence per packed slot: corev *= Mv; Mv *= G2.
#define OCT_SETUP(SFIRST, corev, Mv)                                          \
    {                                                                         \
        const float t0 = dc - (SFIRST);                                       \
        const float S0 = __builtin_amdgcn_exp2f(                              \
            __builtin_fmaf(-L16 * t0, t0, FOFF));                             \
        const float M1 = __builtin_amdgcn_exp2f(                              \
            __builtin_fmaf(TWOLD, t0, -LD2));                                 \
        const float M20 = (M1 * M1) * G1;                                     \
        corev = f2{S0, S0 * M1};                                              \
        Mv    = f2{M20, M20 * GH};                                            \
    }

    float4 cj = sc[lane];
    #pragma unroll 1
    for (int jc = 0; jc < N; jc += 64) {
        // prefetch next chunk (wraps harmlessly on last iter)
        const float4 cjn = sc[((jc + 64) & (N - 1)) + lane];

        const float dx = ci.x - cj.x;
        const float dy = ci.y - cj.y;
        const float dz = ci.z - cj.z;
        const float sq = dx * dx + dy * dy + dz * dz;
        const float d  = __builtin_amdgcn_sqrtf(sq);
        const int spj  = __float_as_int(cj.w);

        const bool valid = (d > 0.0f) && (d <= 5.2f);
        // fc = 0.5*cos(pi*d/5.2)+0.5 ; v_cos takes revolutions: d/10.4
        float fc = 0.5f * __builtin_amdgcn_cosf(d * (1.0f / 10.4f)) + 0.5f;
        fc = valid ? fc : 0.0f;

        const float dc  = fminf(d, 5.2f);      // ladder-safe distance
        const float fcs = fc * SCALE_DN;       // fold 2^-96 unscale into fc
        const f2 fcv = {fcs, fcs};
        const f2 f0 = (spj == 0) ? fcv : z2;
        const f2 f1 = (spj == 1) ? fcv : z2;
        const f2 fm2 = (spj == 2) ? fcv : z2;
        const f2 f3 = (spj == 3) ? fcv : z2;

        f2 c0v, M0v, c1v, M1v;
        OCT_SETUP(0.9f,  c0v, M0v)   // octave 0: r = 0..7  (acc h = 0..3)
        OCT_SETUP(3.05f, c1v, M1v)   // octave 1: r = 8..15 (acc h = 4..7)

        #pragma unroll
        for (int h = 0; h < 4; ++h) {
            acc[0 * 8 + h] += c0v * f0;    // v_pk_fma_f32 x8
            acc[1 * 8 + h] += c0v * f1;
            acc[2 * 8 + h] += c0v * fm2;
            acc[3 * 8 + h] += c0v * f3;
            acc[0 * 8 + 4 + h] += c1v * f0;
            acc[1 * 8 + 4 + h] += c1v * f1;
            acc[2 * 8 + 4 + h] += c1v * fm2;
            acc[3 * 8 + 4 + h] += c1v * f3;
            c0v *= M0v;  M0v *= G2v;       // ladder step (last iter DCE'd)
            c1v *= M1v;  M1v *= G2v;
        }
        cj = cjn;
    }
#undef OCT_SETUP

    // Reduce-scatter: 5 f2 levels (m=32..2), then one float exchange (m=1).
    int cnt = 32;
    #pragma unroll
    for (int m = 32; m >= 2; m >>= 1) {
        const int half = cnt >> 1;
        const bool up = (lane & m) != 0;
        #pragma unroll
        for (int k = 0; k < half; ++k) {
            const f2 keep = up ? acc[k + half] : acc[k];
            const f2 send = up ? acc[k] : acc[k + half];
            f2 r;
            r.x = __shfl_xor(send.x, m, 64);
            r.y = __shfl_xor(send.y, m, 64);
            acc[k] = keep + r;
        }
        cnt = half;
    }
    // acc[0] = features {2t, 2t+1}, t = lane>>1, split by lane parity subsets.
    const bool hi = (lane & 1) != 0;
    const float send = hi ? acc[0].x : acc[0].y;
    const float recv = __shfl_xor(send, 1, 64);
    const float mine = (hi ? acc[0].y : acc[0].x) + recv;

    float* row = out + (size_t)(bb * N + i) * TARGET;
    row[lane] = mine;
    float4* row4 = reinterpret_cast<float4*>(row);
    const float4 z4 = make_float4(0.0f, 0.0f, 0.0f, 0.0f);
    #pragma unroll
    for (int idx = 16 + lane; idx < 252; idx += 64) row4[idx] = z4;
}

extern "C" void kernel_launch(void* const* d_in, const int* in_sizes, int n_in,
                              void* d_out, int out_size, void* d_ws, size_t ws_size,
                              hipStream_t stream) {
    const int*   species     = (const int*)d_in[0];
    const float* coordinates = (const float*)d_in[1];
    float*       out         = (float*)d_out;

    dim3 grid(B * 128), block(256);  // 4 waves = 4 atoms per block
    hipLaunchKernelGGL(aev_radial_kernel, grid, block, 0, stream,
                       species, coordinates, out);
}